// Round 15
// baseline (188.165 us; speedup 1.0000x reference)
//
#include <hip/hip_runtime.h>

#define NN 50000
#define NE 800000
#define HID 128
#define OUTD 64
#define NBK 782      // buckets (dst >> 6)
#define CAP 1408     // pairs/perm capacity per bucket (mean 1023.7, +12 sigma)
#define TILE_E 4096  // edges per binA block
#define XB 3125      // NN*16/256 exact (x float4 chunks)
#define HB 196       // ceil(NE/TILE_E)
#define NPART 8      // BN stat partial buffers

typedef __attribute__((ext_vector_type(8))) short bf16x8;
typedef __attribute__((ext_vector_type(4))) float f32x4;

static __device__ __forceinline__ unsigned short f2bf(float f) {
    unsigned u = __float_as_uint(f);
    unsigned r = (u + 0x7FFFu + ((u >> 16) & 1u)) >> 16;   // RNE
    return (unsigned short)r;
}
static __device__ __forceinline__ float bflo(unsigned u) { return __uint_as_float(u << 16); }
static __device__ __forceinline__ float bfhi(unsigned u) { return __uint_as_float(u & 0xffff0000u); }

#define ACC8(vv)                                            \
    acc[0] += bflo(vv.x); acc[1] += bfhi(vv.x);             \
    acc[2] += bflo(vv.y); acc[3] += bfhi(vv.y);             \
    acc[4] += bflo(vv.z); acc[5] += bfhi(vv.z);             \
    acc[6] += bflo(vv.w); acc[7] += bfhi(vv.w);

// ---------------- fused prep+binA: binA blocks first (long poles), then x2bf | wprep --
// gcur/sums_p/sumsq_p zeroed by preceding hipMemsetAsync. pairs packed: (dstloc<<16)|src.
// pairs stored non-temporally (read once, next kernel) to preserve L2 for xb.
__global__ __launch_bounds__(256) void prep_bin_kernel(
    const float* __restrict__ x, unsigned short* __restrict__ xb,
    const float* __restrict__ W1l, const float* __restrict__ W1r,
    const float* __restrict__ W2l, const float* __restrict__ W2r,
    unsigned short* __restrict__ BT1, unsigned short* __restrict__ BT2,
    const int* __restrict__ src, const int* __restrict__ dst,
    int* __restrict__ gcur, unsigned* __restrict__ pairs)
{
    __shared__ int lcnt[NBK];
    __shared__ int lbase[NBK];
    int blk = blockIdx.x, tid = threadIdx.x;
    if (blk >= HB) {
        int b2 = blk - HB;
        if (b2 < XB) {
            int idx = b2 * 256 + tid;
            int n = idx >> 4, q = idx & 15;
            float4 v = ((const float4*)x)[idx];
            ushort4 o;
            o.x = f2bf(v.x); o.y = f2bf(v.y); o.z = f2bf(v.z); o.w = f2bf(v.w);
            *(ushort4*)(xb + (size_t)n * 64 + q * 4) = o;
        } else {
            int idx = (b2 - XB) * 256 + tid;
            int j = idx >> 7, k = idx & 127;
            float v1 = (k < 64) ? W1l[k * HID + j] : W1r[(k - 64) * HID + j];
            BT1[j * 128 + k] = f2bf(v1);
            float v2 = (j < 64) ? W2l[k * OUTD + j] : W2r[k * OUTD + (j - 64)];
            BT2[j * 128 + k] = f2bf(v2);
        }
        return;
    }
    // ---- binA: bin edges into fixed-capacity bucket regions ----
    int e0 = blk * TILE_E;
    for (int i = tid; i < NBK; i += 256) lcnt[i] = 0;
    __syncthreads();
    int s[16], d[16], loc[16];
#pragma unroll
    for (int i = 0; i < 16; i++) {
        int e = e0 + i * 256 + tid;
        if (e < NE) {
            s[i] = __builtin_nontemporal_load(&src[e]);
            d[i] = __builtin_nontemporal_load(&dst[e]);
            loc[i] = atomicAdd(&lcnt[d[i] >> 6], 1);
        }
    }
    __syncthreads();
    for (int b = tid; b < NBK; b += 256)
        lbase[b] = b * CAP + atomicAdd(&gcur[b], lcnt[b]);
    __syncthreads();
#pragma unroll
    for (int i = 0; i < 16; i++) {
        int e = e0 + i * 256 + tid;
        if (e < NE)
            __builtin_nontemporal_store(
                (unsigned)(((d[i] & 63) << 16) | s[i]),
                &pairs[lbase[d[i] >> 6] + loc[i]]);
    }
}

// ------- fused aggA + conv1, FULL-bucket 512-thread blocks (grid NBK) ----------------
// Phase 1: hist (pairs staged to LDS) / scan / scatter-from-LDS -> permL;
//          persist perm (non-temporal) + deg/start for agg2.
// Phase 2: gather-mean into aggL[64][72] -- all 64 slots in ONE round (8 waves x 8).
// Phase 3: conv1 MFMA, exactly one (tile,jh) task per wave; BN stats -> 8-way partials.
__global__ __launch_bounds__(512) void agg_conv1_kernel(
    const unsigned* __restrict__ pairs, const int* __restrict__ gcur,
    const unsigned short* __restrict__ xb, const unsigned short* __restrict__ BT,
    const float* __restrict__ bias, unsigned short* __restrict__ hpreb,
    float* __restrict__ sums_p, float* __restrict__ sumsq_p,
    unsigned short* __restrict__ permG, unsigned short* __restrict__ degG,
    unsigned short* __restrict__ startG)
{
    __shared__ int lcnt[64];
    __shared__ int startL[64];
    __shared__ int degL[64];
    __shared__ int lcur[64];
    __shared__ __align__(16) unsigned pairsL[CAP];
    __shared__ __align__(4) unsigned short permL[CAP];
    __shared__ __align__(16) unsigned short aggL[64][72];   // pad 64->72: 2-way banks
    __shared__ float red_s[4][128];
    __shared__ float red_q[4][128];
    int b = blockIdx.x, tid = threadIdx.x;
    int lo = b * CAP;
    int cnt = gcur[b];
    if (tid < 64) lcnt[tid] = 0;
    __syncthreads();
    for (int i = tid; i < cnt; i += 512) {
        unsigned p = pairs[lo + i];
        pairsL[i] = p;
        atomicAdd(&lcnt[p >> 16], 1);
    }
    __syncthreads();
    if (tid < 64) {
        int v = lcnt[tid];
        int s = v;
#pragma unroll
        for (int off = 1; off < 64; off <<= 1) {
            int t = __shfl_up(s, off, 64);
            if (tid >= off) s += t;
        }
        startL[tid] = s - v;
        degL[tid] = v;
        lcur[tid] = s - v;
        degG[b * 64 + tid] = (unsigned short)v;
        startG[b * 64 + tid] = (unsigned short)(s - v);
    }
    __syncthreads();
    for (int i = tid; i < cnt; i += 512) {
        unsigned p = pairsL[i];
        int pos = atomicAdd(&lcur[p >> 16], 1);
        permL[pos] = (unsigned short)(p & 0xffffu);
    }
    __syncthreads();
    // persist perm (coalesced u32 non-temporal) -- read only by agg2, 2 dispatches later
    int cu = (cnt + 1) >> 1;
    unsigned* pgb = (unsigned*)(permG + (size_t)b * CAP);
    for (int i = tid; i < cu; i += 512)
        __builtin_nontemporal_store(((const unsigned*)permL)[i], &pgb[i]);
    // ---- gather-mean into aggL: 8 waves x 8 slots = 64 nodes, one round ----
    int lane = tid & 63, w = tid >> 6;
    int g = lane >> 3;        // node slot within wave
    int q = lane & 7;         // 8 bf16 cols per lane
    int ln = w * 8 + g;       // 0..63
    const unsigned short* fbase = xb + q * 8;
    {
        int rs = startL[ln];
        int deg = degL[ln];
        float acc[8];
#pragma unroll
        for (int t = 0; t < 8; t++) acc[t] = 0.f;
        int i = 0;
        for (; i + 3 < deg; i += 4) {
            int s0 = permL[rs + i];
            int s1 = permL[rs + i + 1];
            int s2 = permL[rs + i + 2];
            int s3 = permL[rs + i + 3];
            uint4 v0 = *(const uint4*)(fbase + (size_t)s0 * 64);
            uint4 v1 = *(const uint4*)(fbase + (size_t)s1 * 64);
            uint4 v2 = *(const uint4*)(fbase + (size_t)s2 * 64);
            uint4 v3 = *(const uint4*)(fbase + (size_t)s3 * 64);
            ACC8(v0) ACC8(v1) ACC8(v2) ACC8(v3)
        }
        for (; i < deg; i++) {
            int s0 = permL[rs + i];
            uint4 v0 = *(const uint4*)(fbase + (size_t)s0 * 64);
            ACC8(v0)
        }
        float inv = (deg > 0) ? (1.0f / (float)deg) : 0.f;
        uint4 o;
        o.x = (unsigned)f2bf(acc[0] * inv) | ((unsigned)f2bf(acc[1] * inv) << 16);
        o.y = (unsigned)f2bf(acc[2] * inv) | ((unsigned)f2bf(acc[3] * inv) << 16);
        o.z = (unsigned)f2bf(acc[4] * inv) | ((unsigned)f2bf(acc[5] * inv) << 16);
        o.w = (unsigned)f2bf(acc[6] * inv) | ((unsigned)f2bf(acc[7] * inv) << 16);
        *(uint4*)&aggL[ln][q * 8] = o;
    }
    __syncthreads();
    // ---- conv1: wave w -> jh = w&1, tile t = w>>1 (one task per wave, 8 waves) ----
    int nl = lane & 15, ko = lane >> 4;
    int jh = w & 1, t = w >> 1;
    bf16x8 bfr[4][4];
    const unsigned short* bbase = BT + (size_t)(jh * 64 + nl) * 128 + ko * 8;
#pragma unroll
    for (int jg = 0; jg < 4; jg++)
#pragma unroll
        for (int ks = 0; ks < 4; ks++)
            bfr[jg][ks] = *(const bf16x8*)(bbase + jg * 16 * 128 + ks * 32);
    float4 bias4[4];
#pragma unroll
    for (int jg = 0; jg < 4; jg++)
        bias4[jg] = *(const float4*)(bias + jh * 64 + jg * 16 + ko * 4);
    float s_sum[16], s_sq[16];
#pragma unroll
    for (int tt = 0; tt < 16; tt++) { s_sum[tt] = 0.f; s_sq[tt] = 0.f; }
    int n_g = b * 64 + t * 16 + nl;
    if (n_g < NN) {   // NN%16==0 -> whole tile valid or whole tile invalid
        bf16x8 a[4];
#pragma unroll
        for (int ks = 0; ks < 2; ks++)
            a[ks] = *(const bf16x8*)&aggL[t * 16 + nl][ks * 32 + ko * 8];
        const unsigned short* xrow = xb + (size_t)n_g * 64 + ko * 8;
#pragma unroll
        for (int ks = 2; ks < 4; ks++)
            a[ks] = *(const bf16x8*)(xrow + (ks - 2) * 32);
#pragma unroll
        for (int jg = 0; jg < 4; jg++) {
            f32x4 acc = {0.f, 0.f, 0.f, 0.f};
#pragma unroll
            for (int ks = 0; ks < 4; ks++)
                acc = __builtin_amdgcn_mfma_f32_16x16x32_bf16(bfr[jg][ks], a[ks], acc, 0, 0, 0);
            float v0 = acc[0] + bias4[jg].x;
            float v1 = acc[1] + bias4[jg].y;
            float v2 = acc[2] + bias4[jg].z;
            float v3 = acc[3] + bias4[jg].w;
            s_sum[jg * 4 + 0] += v0; s_sq[jg * 4 + 0] += v0 * v0;
            s_sum[jg * 4 + 1] += v1; s_sq[jg * 4 + 1] += v1 * v1;
            s_sum[jg * 4 + 2] += v2; s_sq[jg * 4 + 2] += v2 * v2;
            s_sum[jg * 4 + 3] += v3; s_sq[jg * 4 + 3] += v3 * v3;
            uint2 pk;
            pk.x = (unsigned)f2bf(v0) | ((unsigned)f2bf(v1) << 16);
            pk.y = (unsigned)f2bf(v2) | ((unsigned)f2bf(v3) << 16);
            *(uint2*)(hpreb + (size_t)n_g * 128 + jh * 64 + jg * 16 + ko * 4) = pk;
        }
    }
    // ---- BN stats: each (t,jh) half-row written by exactly one wave (no zero-init) ---
#pragma unroll
    for (int jg = 0; jg < 4; jg++) {
#pragma unroll
        for (int r = 0; r < 4; r++) {
            float v = s_sum[jg * 4 + r];
            v += __shfl_xor(v, 1, 64);
            v += __shfl_xor(v, 2, 64);
            v += __shfl_xor(v, 4, 64);
            v += __shfl_xor(v, 8, 64);
            float w2 = s_sq[jg * 4 + r];
            w2 += __shfl_xor(w2, 1, 64);
            w2 += __shfl_xor(w2, 2, 64);
            w2 += __shfl_xor(w2, 4, 64);
            w2 += __shfl_xor(w2, 8, 64);
            if (nl == 0) {
                red_s[t][jh * 64 + jg * 16 + ko * 4 + r] = v;
                red_q[t][jh * 64 + jg * 16 + ko * 4 + r] = w2;
            }
        }
    }
    __syncthreads();
    if (tid < 128) {
        float v = red_s[0][tid] + red_s[1][tid] + red_s[2][tid] + red_s[3][tid];
        atomicAdd(&sums_p[(b & (NPART - 1)) * 128 + tid], v);
    } else if (tid < 256) {
        int j = tid - 128;
        float v = red_q[0][j] + red_q[1][j] + red_q[2][j] + red_q[3][j];
        atomicAdd(&sumsq_p[(b & (NPART - 1)) * 128 + j], v);
    }
}

// unpack raw bf16x8 (as uint4), apply BN scale/shift + ReLU, repack to bf16x8
static __device__ __forceinline__ bf16x8 bnrelu8(uint4 v, const float* sc,
                                                 const float* sh, int j0) {
    float f[8];
    f[0] = bflo(v.x); f[1] = bfhi(v.x);
    f[2] = bflo(v.y); f[3] = bfhi(v.y);
    f[4] = bflo(v.z); f[5] = bfhi(v.z);
    f[6] = bflo(v.w); f[7] = bfhi(v.w);
#pragma unroll
    for (int t = 0; t < 8; t++) {
        float h = f[t] * sc[j0 + t] + sh[j0 + t];
        f[t] = h > 0.f ? h : 0.f;
    }
    unsigned r01 = (unsigned)f2bf(f[0]) | ((unsigned)f2bf(f[1]) << 16);
    unsigned r23 = (unsigned)f2bf(f[2]) | ((unsigned)f2bf(f[3]) << 16);
    unsigned r45 = (unsigned)f2bf(f[4]) | ((unsigned)f2bf(f[5]) << 16);
    unsigned r67 = (unsigned)f2bf(f[6]) | ((unsigned)f2bf(f[7]) << 16);
    uint4 o = make_uint4(r01, r23, r45, r67);
    return *(bf16x8*)&o;
}

// ---------------- conv2 (BN+ReLU fused on A-load): [p | self] = relu(bn(hpre)) @ BT2 --
// jh=0 -> p bf16 into pb (stride 64); jh=1 -> f32 out + b2.  Reads 8-way stat partials.
__global__ __launch_bounds__(256) void conv2_kernel(
    const unsigned short* __restrict__ A, const unsigned short* __restrict__ BT,
    const float* __restrict__ bias,
    unsigned short* __restrict__ pb, float* __restrict__ outf,
    const float* __restrict__ sums_p, const float* __restrict__ sumsq_p,
    const float* __restrict__ gamma, const float* __restrict__ beta)
{
    __shared__ float sc[128], sh[128];
    int tid = threadIdx.x;
    int wid = tid >> 6, lane = tid & 63;
    int nl = lane & 15, ko = lane >> 4;
    if (tid < 128) {
        float s = 0.f, qq = 0.f;
#pragma unroll
        for (int p = 0; p < NPART; p++) {
            s  += sums_p[p * 128 + tid];
            qq += sumsq_p[p * 128 + tid];
        }
        float inv_n = 1.0f / (float)NN;
        float mu = s * inv_n;
        float var = qq * inv_n - mu * mu;
        float sf = gamma[tid] * rsqrtf(var + 1e-5f);
        sc[tid] = sf;
        sh[tid] = beta[tid] - mu * sf;
    }
    __syncthreads();
    int gw = blockIdx.x * 4 + wid;
    int jh = gw & 1;
    int tstride = (gridDim.x * 4) >> 1;
    const int tiles = NN / 16;             // 3125 exact
    bf16x8 bfr[4][4];
    const unsigned short* bbase = BT + (size_t)(jh * 64 + nl) * 128 + ko * 8;
#pragma unroll
    for (int jg = 0; jg < 4; jg++)
#pragma unroll
        for (int ks = 0; ks < 4; ks++)
            bfr[jg][ks] = *(const bf16x8*)(bbase + jg * 16 * 128 + ks * 32);
    float4 bias4[4];
#pragma unroll
    for (int jg = 0; jg < 4; jg++) {
        if (jh) bias4[jg] = *(const float4*)(bias + jg * 16 + ko * 4);
        else    bias4[jg] = make_float4(0.f, 0.f, 0.f, 0.f);
    }
    int tile = gw >> 1;
    uint4 a[4];
    if (tile < tiles) {
        const unsigned short* arow = A + (size_t)(tile * 16 + nl) * 128 + ko * 8;
#pragma unroll
        for (int ks = 0; ks < 4; ks++) a[ks] = *(const uint4*)(arow + ks * 32);
    }
    while (tile < tiles) {
        int nxt = tile + tstride;
        uint4 an[4];
        if (nxt < tiles) {
            const unsigned short* arow = A + (size_t)(nxt * 16 + nl) * 128 + ko * 8;
#pragma unroll
            for (int ks = 0; ks < 4; ks++) an[ks] = *(const uint4*)(arow + ks * 32);
        }
        bf16x8 af[4];
#pragma unroll
        for (int ks = 0; ks < 4; ks++)
            af[ks] = bnrelu8(a[ks], sc, sh, ks * 32 + ko * 8);
        int n_g = tile * 16 + nl;
#pragma unroll
        for (int jg = 0; jg < 4; jg++) {
            f32x4 acc = {0.f, 0.f, 0.f, 0.f};
#pragma unroll
            for (int ks = 0; ks < 4; ks++)
                acc = __builtin_amdgcn_mfma_f32_16x16x32_bf16(bfr[jg][ks], af[ks], acc, 0, 0, 0);
            float v0 = acc[0] + bias4[jg].x;
            float v1 = acc[1] + bias4[jg].y;
            float v2 = acc[2] + bias4[jg].z;
            float v3 = acc[3] + bias4[jg].w;
            if (jh == 0) {
                uint2 pk;
                pk.x = (unsigned)f2bf(v0) | ((unsigned)f2bf(v1) << 16);
                pk.y = (unsigned)f2bf(v2) | ((unsigned)f2bf(v3) << 16);
                *(uint2*)(pb + (size_t)n_g * 64 + jg * 16 + ko * 4) = pk;
            } else {
                float4 o = make_float4(v0, v1, v2, v3);
                *(float4*)(outf + (size_t)n_g * 64 + jg * 16 + ko * 4) = o;
            }
        }
#pragma unroll
        for (int ks = 0; ks < 4; ks++) a[ks] = an[ks];
        tile = nxt;
    }
}

// ---------------- agg2: CSR-reuse gather of p rows, FULL-bucket 512-thread blocks ----
__global__ __launch_bounds__(512) void agg2_kernel(
    const unsigned short* __restrict__ permG, const int* __restrict__ gcur,
    const unsigned short* __restrict__ degG, const unsigned short* __restrict__ startG,
    const unsigned short* __restrict__ pb, float* __restrict__ out)
{
    __shared__ __align__(4) unsigned short permL[CAP];
    __shared__ int startL[64];
    __shared__ int degL[64];
    int b = blockIdx.x, tid = threadIdx.x;
    int cnt = gcur[b];
    if (tid < 64) {
        startL[tid] = startG[b * 64 + tid];
        degL[tid] = degG[b * 64 + tid];
    }
    int cu = (cnt + 1) >> 1;
    const unsigned* pgb = (const unsigned*)(permG + (size_t)b * CAP);
    for (int i = tid; i < cu; i += 512)
        ((unsigned*)permL)[i] = __builtin_nontemporal_load(&pgb[i]);
    __syncthreads();
    int lane = tid & 63, w = tid >> 6;
    int g = lane >> 3;
    int q = lane & 7;
    int ln = w * 8 + g;                    // 0..63
    int node = b * 64 + ln;
    const unsigned short* fbase = pb + q * 8;
    int rs = startL[ln];
    int deg = degL[ln];
    float acc[8];
#pragma unroll
    for (int t = 0; t < 8; t++) acc[t] = 0.f;
    int i = 0;
    for (; i + 3 < deg; i += 4) {
        int s0 = permL[rs + i];
        int s1 = permL[rs + i + 1];
        int s2 = permL[rs + i + 2];
        int s3 = permL[rs + i + 3];
        uint4 v0 = *(const uint4*)(fbase + (size_t)s0 * 64);
        uint4 v1 = *(const uint4*)(fbase + (size_t)s1 * 64);
        uint4 v2 = *(const uint4*)(fbase + (size_t)s2 * 64);
        uint4 v3 = *(const uint4*)(fbase + (size_t)s3 * 64);
        ACC8(v0) ACC8(v1) ACC8(v2) ACC8(v3)
    }
    for (; i < deg; i++) {
        int s0 = permL[rs + i];
        uint4 v0 = *(const uint4*)(fbase + (size_t)s0 * 64);
        ACC8(v0)
    }
    if (node < NN) {
        float inv = (deg > 0) ? (1.0f / (float)deg) : 0.f;
        float4* op = (float4*)(out + (size_t)node * 64 + q * 8);
        float4 o0 = op[0], o1 = op[1];
        o0.x += acc[0] * inv; o0.y += acc[1] * inv;
        o0.z += acc[2] * inv; o0.w += acc[3] * inv;
        o1.x += acc[4] * inv; o1.y += acc[5] * inv;
        o1.z += acc[6] * inv; o1.w += acc[7] * inv;
        op[0] = o0; op[1] = o1;
    }
}

extern "C" void kernel_launch(void* const* d_in, const int* in_sizes, int n_in,
                              void* d_out, int out_size, void* d_ws, size_t ws_size,
                              hipStream_t stream) {
    const float* x     = (const float*)d_in[0];
    const int*   ei    = (const int*)d_in[1];
    const float* W1l   = (const float*)d_in[2];
    const float* b1    = (const float*)d_in[3];
    const float* W1r   = (const float*)d_in[4];
    const float* gamma = (const float*)d_in[5];
    const float* beta  = (const float*)d_in[6];
    const float* W2l   = (const float*)d_in[7];
    const float* b2    = (const float*)d_in[8];
    const float* W2r   = (const float*)d_in[9];
    float* out = (float*)d_out;

    // workspace layout (~32.5 MB)
    char* wsb = (char*)d_ws;
    int*   gcur    = (int*)wsb;                                  // 784 ints (pad 4KB)
    float* sums_p  = (float*)(wsb + 4096);                       // 8*128 f32 (4 KB)
    float* sumsq_p = (float*)(wsb + 8192);                       // 8*128 f32 (4 KB)
    unsigned* pairs = (unsigned*)(wsb + 12288);                  // NBK*CAP u32 (4.4 MB)
    unsigned short* permG  = (unsigned short*)((char*)pairs + (size_t)NBK * CAP * 4); // u16
    unsigned short* degG   = permG + (size_t)NBK * CAP;          // NBK*64 u16
    unsigned short* startG = degG + (size_t)NBK * 64;            // NBK*64 u16
    unsigned short* xb     = startG + (size_t)NBK * 64;          // NN*64 bf16 (6.4 MB)
    unsigned short* hpreb  = xb + (size_t)NN * 64;               // NN*128 bf16 (12.8 MB)
    unsigned short* pbuf   = hpreb + (size_t)NN * 128;           // NN*64 bf16 (6.4 MB)
    unsigned short* BT1    = pbuf + (size_t)NN * 64;             // 128*128 bf16
    unsigned short* BT2    = BT1 + 128 * 128;                    // 128*128 bf16

    const int* srcp = ei;
    const int* dstp = ei + NE;

    // zero gcur + sums_p + sumsq_p
    hipMemsetAsync(d_ws, 0, 12288, stream);

    prep_bin_kernel<<<HB + XB + 64, 256, 0, stream>>>(x, xb, W1l, W1r, W2l, W2r,
                                                      BT1, BT2, srcp, dstp, gcur, pairs);
    // aggA + conv1 fused, full-bucket 512-thread blocks (pairs LDS-staged, nt persists)
    agg_conv1_kernel<<<NBK, 512, 0, stream>>>(pairs, gcur, xb, BT1, b1, hpreb,
                                              sums_p, sumsq_p, permG, degG, startG);
    // conv2 (BN fused on A-load): p bf16 -> pbuf, self+b2 -> out
    conv2_kernel<<<512, 256, 0, stream>>>(hpreb, BT2, b2, pbuf, out,
                                          sums_p, sumsq_p, gamma, beta);
    // agg2: CSR-reuse gather pbuf rows -> out += mean, full-bucket 512-thread blocks
    agg2_kernel<<<NBK, 512, 0, stream>>>(permG, gcur, degG, startG, pbuf, out);
}

// Round 16
// 168.937 us; speedup vs baseline: 1.1138x; 1.1138x over previous
//
#include <hip/hip_runtime.h>

#define NN 50000
#define NE 800000
#define HID 128
#define OUTD 64
#define NBK 782      // buckets (dst >> 6)
#define CAP 1408     // pairs/perm capacity per bucket (mean 1023.7, +12 sigma)
#define TILE_E 4096  // edges per binA block
#define XB 3125      // NN*16/256 exact (x float4 chunks)
#define HB 196       // ceil(NE/TILE_E)
#define NPART 8      // BN stat partial buffers

typedef __attribute__((ext_vector_type(8))) short bf16x8;
typedef __attribute__((ext_vector_type(4))) float f32x4;

static __device__ __forceinline__ unsigned short f2bf(float f) {
    unsigned u = __float_as_uint(f);
    unsigned r = (u + 0x7FFFu + ((u >> 16) & 1u)) >> 16;   // RNE
    return (unsigned short)r;
}
static __device__ __forceinline__ float bflo(unsigned u) { return __uint_as_float(u << 16); }
static __device__ __forceinline__ float bfhi(unsigned u) { return __uint_as_float(u & 0xffff0000u); }

#define ACC8(vv)                                            \
    acc[0] += bflo(vv.x); acc[1] += bfhi(vv.x);             \
    acc[2] += bflo(vv.y); acc[3] += bfhi(vv.y);             \
    acc[4] += bflo(vv.z); acc[5] += bfhi(vv.z);             \
    acc[6] += bflo(vv.w); acc[7] += bfhi(vv.w);

// ---------------- fused prep+binA: binA blocks first (long poles), then x2bf | wprep --
// gcur/sums_p/sumsq_p zeroed by preceding hipMemsetAsync. pairs packed: (dstloc<<16)|src.
__global__ __launch_bounds__(256) void prep_bin_kernel(
    const float* __restrict__ x, unsigned short* __restrict__ xb,
    const float* __restrict__ W1l, const float* __restrict__ W1r,
    const float* __restrict__ W2l, const float* __restrict__ W2r,
    unsigned short* __restrict__ BT1, unsigned short* __restrict__ BT2,
    const int* __restrict__ src, const int* __restrict__ dst,
    int* __restrict__ gcur, unsigned* __restrict__ pairs)
{
    __shared__ int lcnt[NBK];
    __shared__ int lbase[NBK];
    int blk = blockIdx.x, tid = threadIdx.x;
    if (blk >= HB) {
        int b2 = blk - HB;
        if (b2 < XB) {
            int idx = b2 * 256 + tid;
            int n = idx >> 4, q = idx & 15;
            float4 v = ((const float4*)x)[idx];
            ushort4 o;
            o.x = f2bf(v.x); o.y = f2bf(v.y); o.z = f2bf(v.z); o.w = f2bf(v.w);
            *(ushort4*)(xb + (size_t)n * 64 + q * 4) = o;
        } else {
            int idx = (b2 - XB) * 256 + tid;
            int j = idx >> 7, k = idx & 127;
            float v1 = (k < 64) ? W1l[k * HID + j] : W1r[(k - 64) * HID + j];
            BT1[j * 128 + k] = f2bf(v1);
            float v2 = (j < 64) ? W2l[k * OUTD + j] : W2r[k * OUTD + (j - 64)];
            BT2[j * 128 + k] = f2bf(v2);
        }
        return;
    }
    // ---- binA: bin edges into fixed-capacity bucket regions ----
    int e0 = blk * TILE_E;
    for (int i = tid; i < NBK; i += 256) lcnt[i] = 0;
    __syncthreads();
    int s[16], d[16], loc[16];
#pragma unroll
    for (int i = 0; i < 16; i++) {
        int e = e0 + i * 256 + tid;
        if (e < NE) {
            s[i] = __builtin_nontemporal_load(&src[e]);
            d[i] = __builtin_nontemporal_load(&dst[e]);
            loc[i] = atomicAdd(&lcnt[d[i] >> 6], 1);
        }
    }
    __syncthreads();
    for (int b = tid; b < NBK; b += 256)
        lbase[b] = b * CAP + atomicAdd(&gcur[b], lcnt[b]);
    __syncthreads();
#pragma unroll
    for (int i = 0; i < 16; i++) {
        int e = e0 + i * 256 + tid;
        if (e < NE)
            pairs[lbase[d[i] >> 6] + loc[i]] =
                (unsigned)(((d[i] & 63) << 16) | s[i]);
    }
}

// ------- fused aggA + conv1, FULL-bucket 512-thread blocks (grid NBK) ----------------
// Phase 1 (2 iters): hist/scan/scatter -> permL; persist perm/deg/start for agg2.
// Phase 2: gather-mean into aggL[64][72] -- all 64 slots in ONE round (8 waves x 8).
// Phase 3: conv1 MFMA, exactly one (tile,jh) task per wave; BN stats -> 8-way partials.
__global__ __launch_bounds__(512) void agg_conv1_kernel(
    const unsigned* __restrict__ pairs, const int* __restrict__ gcur,
    const unsigned short* __restrict__ xb, const unsigned short* __restrict__ BT,
    const float* __restrict__ bias, unsigned short* __restrict__ hpreb,
    float* __restrict__ sums_p, float* __restrict__ sumsq_p,
    unsigned short* __restrict__ permG, unsigned short* __restrict__ degG,
    unsigned short* __restrict__ startG)
{
    __shared__ int lcnt[64];
    __shared__ int startL[64];
    __shared__ int degL[64];
    __shared__ int lcur[64];
    __shared__ __align__(4) unsigned short permL[CAP];
    __shared__ __align__(16) unsigned short aggL[64][72];   // pad 64->72: 2-way banks
    __shared__ float red_s[4][128];
    __shared__ float red_q[4][128];
    int b = blockIdx.x, tid = threadIdx.x;
    int lo = b * CAP;
    int cnt = gcur[b];
    if (tid < 64) lcnt[tid] = 0;
    __syncthreads();
    for (int i = tid; i < cnt; i += 512)
        atomicAdd(&lcnt[pairs[lo + i] >> 16], 1);
    __syncthreads();
    if (tid < 64) {
        int v = lcnt[tid];
        int s = v;
#pragma unroll
        for (int off = 1; off < 64; off <<= 1) {
            int t = __shfl_up(s, off, 64);
            if (tid >= off) s += t;
        }
        startL[tid] = s - v;
        degL[tid] = v;
        lcur[tid] = s - v;
        degG[b * 64 + tid] = (unsigned short)v;
        startG[b * 64 + tid] = (unsigned short)(s - v);
    }
    __syncthreads();
    for (int i = tid; i < cnt; i += 512) {
        unsigned p = pairs[lo + i];
        int pos = atomicAdd(&lcur[p >> 16], 1);
        permL[pos] = (unsigned short)(p & 0xffffu);
    }
    __syncthreads();
    // persist perm (coalesced u32 copies) -- concurrent with gather (both read permL)
    int cu = (cnt + 1) >> 1;
    unsigned* pgb = (unsigned*)(permG + (size_t)b * CAP);
    for (int i = tid; i < cu; i += 512)
        pgb[i] = ((const unsigned*)permL)[i];
    // ---- gather-mean into aggL: 8 waves x 8 slots = 64 nodes, one round ----
    int lane = tid & 63, w = tid >> 6;
    int g = lane >> 3;        // node slot within wave
    int q = lane & 7;         // 8 bf16 cols per lane
    int ln = w * 8 + g;       // 0..63
    const unsigned short* fbase = xb + q * 8;
    {
        int rs = startL[ln];
        int deg = degL[ln];
        float acc[8];
#pragma unroll
        for (int t = 0; t < 8; t++) acc[t] = 0.f;
        int i = 0;
        for (; i + 3 < deg; i += 4) {
            int s0 = permL[rs + i];
            int s1 = permL[rs + i + 1];
            int s2 = permL[rs + i + 2];
            int s3 = permL[rs + i + 3];
            uint4 v0 = *(const uint4*)(fbase + (size_t)s0 * 64);
            uint4 v1 = *(const uint4*)(fbase + (size_t)s1 * 64);
            uint4 v2 = *(const uint4*)(fbase + (size_t)s2 * 64);
            uint4 v3 = *(const uint4*)(fbase + (size_t)s3 * 64);
            ACC8(v0) ACC8(v1) ACC8(v2) ACC8(v3)
        }
        for (; i < deg; i++) {
            int s0 = permL[rs + i];
            uint4 v0 = *(const uint4*)(fbase + (size_t)s0 * 64);
            ACC8(v0)
        }
        float inv = (deg > 0) ? (1.0f / (float)deg) : 0.f;
        uint4 o;
        o.x = (unsigned)f2bf(acc[0] * inv) | ((unsigned)f2bf(acc[1] * inv) << 16);
        o.y = (unsigned)f2bf(acc[2] * inv) | ((unsigned)f2bf(acc[3] * inv) << 16);
        o.z = (unsigned)f2bf(acc[4] * inv) | ((unsigned)f2bf(acc[5] * inv) << 16);
        o.w = (unsigned)f2bf(acc[6] * inv) | ((unsigned)f2bf(acc[7] * inv) << 16);
        *(uint4*)&aggL[ln][q * 8] = o;
    }
    __syncthreads();
    // ---- conv1: wave w -> jh = w&1, tile t = w>>1 (one task per wave, 8 waves) ----
    int nl = lane & 15, ko = lane >> 4;
    int jh = w & 1, t = w >> 1;
    bf16x8 bfr[4][4];
    const unsigned short* bbase = BT + (size_t)(jh * 64 + nl) * 128 + ko * 8;
#pragma unroll
    for (int jg = 0; jg < 4; jg++)
#pragma unroll
        for (int ks = 0; ks < 4; ks++)
            bfr[jg][ks] = *(const bf16x8*)(bbase + jg * 16 * 128 + ks * 32);
    float4 bias4[4];
#pragma unroll
    for (int jg = 0; jg < 4; jg++)
        bias4[jg] = *(const float4*)(bias + jh * 64 + jg * 16 + ko * 4);
    float s_sum[16], s_sq[16];
#pragma unroll
    for (int tt = 0; tt < 16; tt++) { s_sum[tt] = 0.f; s_sq[tt] = 0.f; }
    int n_g = b * 64 + t * 16 + nl;
    if (n_g < NN) {   // NN%16==0 -> whole tile valid or whole tile invalid
        bf16x8 a[4];
#pragma unroll
        for (int ks = 0; ks < 2; ks++)
            a[ks] = *(const bf16x8*)&aggL[t * 16 + nl][ks * 32 + ko * 8];
        const unsigned short* xrow = xb + (size_t)n_g * 64 + ko * 8;
#pragma unroll
        for (int ks = 2; ks < 4; ks++)
            a[ks] = *(const bf16x8*)(xrow + (ks - 2) * 32);
#pragma unroll
        for (int jg = 0; jg < 4; jg++) {
            f32x4 acc = {0.f, 0.f, 0.f, 0.f};
#pragma unroll
            for (int ks = 0; ks < 4; ks++)
                acc = __builtin_amdgcn_mfma_f32_16x16x32_bf16(bfr[jg][ks], a[ks], acc, 0, 0, 0);
            float v0 = acc[0] + bias4[jg].x;
            float v1 = acc[1] + bias4[jg].y;
            float v2 = acc[2] + bias4[jg].z;
            float v3 = acc[3] + bias4[jg].w;
            s_sum[jg * 4 + 0] += v0; s_sq[jg * 4 + 0] += v0 * v0;
            s_sum[jg * 4 + 1] += v1; s_sq[jg * 4 + 1] += v1 * v1;
            s_sum[jg * 4 + 2] += v2; s_sq[jg * 4 + 2] += v2 * v2;
            s_sum[jg * 4 + 3] += v3; s_sq[jg * 4 + 3] += v3 * v3;
            uint2 pk;
            pk.x = (unsigned)f2bf(v0) | ((unsigned)f2bf(v1) << 16);
            pk.y = (unsigned)f2bf(v2) | ((unsigned)f2bf(v3) << 16);
            *(uint2*)(hpreb + (size_t)n_g * 128 + jh * 64 + jg * 16 + ko * 4) = pk;
        }
    }
    // ---- BN stats: each (t,jh) half-row written by exactly one wave (no zero-init) ---
#pragma unroll
    for (int jg = 0; jg < 4; jg++) {
#pragma unroll
        for (int r = 0; r < 4; r++) {
            float v = s_sum[jg * 4 + r];
            v += __shfl_xor(v, 1, 64);
            v += __shfl_xor(v, 2, 64);
            v += __shfl_xor(v, 4, 64);
            v += __shfl_xor(v, 8, 64);
            float w2 = s_sq[jg * 4 + r];
            w2 += __shfl_xor(w2, 1, 64);
            w2 += __shfl_xor(w2, 2, 64);
            w2 += __shfl_xor(w2, 4, 64);
            w2 += __shfl_xor(w2, 8, 64);
            if (nl == 0) {
                red_s[t][jh * 64 + jg * 16 + ko * 4 + r] = v;
                red_q[t][jh * 64 + jg * 16 + ko * 4 + r] = w2;
            }
        }
    }
    __syncthreads();
    if (tid < 128) {
        float v = red_s[0][tid] + red_s[1][tid] + red_s[2][tid] + red_s[3][tid];
        atomicAdd(&sums_p[(b & (NPART - 1)) * 128 + tid], v);
    } else if (tid < 256) {
        int j = tid - 128;
        float v = red_q[0][j] + red_q[1][j] + red_q[2][j] + red_q[3][j];
        atomicAdd(&sumsq_p[(b & (NPART - 1)) * 128 + j], v);
    }
}

// unpack raw bf16x8 (as uint4), apply BN scale/shift + ReLU, repack to bf16x8
static __device__ __forceinline__ bf16x8 bnrelu8(uint4 v, const float* sc,
                                                 const float* sh, int j0) {
    float f[8];
    f[0] = bflo(v.x); f[1] = bfhi(v.x);
    f[2] = bflo(v.y); f[3] = bfhi(v.y);
    f[4] = bflo(v.z); f[5] = bfhi(v.z);
    f[6] = bflo(v.w); f[7] = bfhi(v.w);
#pragma unroll
    for (int t = 0; t < 8; t++) {
        float h = f[t] * sc[j0 + t] + sh[j0 + t];
        f[t] = h > 0.f ? h : 0.f;
    }
    unsigned r01 = (unsigned)f2bf(f[0]) | ((unsigned)f2bf(f[1]) << 16);
    unsigned r23 = (unsigned)f2bf(f[2]) | ((unsigned)f2bf(f[3]) << 16);
    unsigned r45 = (unsigned)f2bf(f[4]) | ((unsigned)f2bf(f[5]) << 16);
    unsigned r67 = (unsigned)f2bf(f[6]) | ((unsigned)f2bf(f[7]) << 16);
    uint4 o = make_uint4(r01, r23, r45, r67);
    return *(bf16x8*)&o;
}

// ---------------- conv2 (BN+ReLU fused on A-load): [p | self] = relu(bn(hpre)) @ BT2 --
// jh=0 -> p bf16 into pb (stride 64); jh=1 -> f32 out + b2.  Reads 8-way stat partials.
__global__ __launch_bounds__(256) void conv2_kernel(
    const unsigned short* __restrict__ A, const unsigned short* __restrict__ BT,
    const float* __restrict__ bias,
    unsigned short* __restrict__ pb, float* __restrict__ outf,
    const float* __restrict__ sums_p, const float* __restrict__ sumsq_p,
    const float* __restrict__ gamma, const float* __restrict__ beta)
{
    __shared__ float sc[128], sh[128];
    int tid = threadIdx.x;
    int wid = tid >> 6, lane = tid & 63;
    int nl = lane & 15, ko = lane >> 4;
    if (tid < 128) {
        float s = 0.f, qq = 0.f;
#pragma unroll
        for (int p = 0; p < NPART; p++) {
            s  += sums_p[p * 128 + tid];
            qq += sumsq_p[p * 128 + tid];
        }
        float inv_n = 1.0f / (float)NN;
        float mu = s * inv_n;
        float var = qq * inv_n - mu * mu;
        float sf = gamma[tid] * rsqrtf(var + 1e-5f);
        sc[tid] = sf;
        sh[tid] = beta[tid] - mu * sf;
    }
    __syncthreads();
    int gw = blockIdx.x * 4 + wid;
    int jh = gw & 1;
    int tstride = (gridDim.x * 4) >> 1;
    const int tiles = NN / 16;             // 3125 exact
    bf16x8 bfr[4][4];
    const unsigned short* bbase = BT + (size_t)(jh * 64 + nl) * 128 + ko * 8;
#pragma unroll
    for (int jg = 0; jg < 4; jg++)
#pragma unroll
        for (int ks = 0; ks < 4; ks++)
            bfr[jg][ks] = *(const bf16x8*)(bbase + jg * 16 * 128 + ks * 32);
    float4 bias4[4];
#pragma unroll
    for (int jg = 0; jg < 4; jg++) {
        if (jh) bias4[jg] = *(const float4*)(bias + jg * 16 + ko * 4);
        else    bias4[jg] = make_float4(0.f, 0.f, 0.f, 0.f);
    }
    int tile = gw >> 1;
    uint4 a[4];
    if (tile < tiles) {
        const unsigned short* arow = A + (size_t)(tile * 16 + nl) * 128 + ko * 8;
#pragma unroll
        for (int ks = 0; ks < 4; ks++) a[ks] = *(const uint4*)(arow + ks * 32);
    }
    while (tile < tiles) {
        int nxt = tile + tstride;
        uint4 an[4];
        if (nxt < tiles) {
            const unsigned short* arow = A + (size_t)(nxt * 16 + nl) * 128 + ko * 8;
#pragma unroll
            for (int ks = 0; ks < 4; ks++) an[ks] = *(const uint4*)(arow + ks * 32);
        }
        bf16x8 af[4];
#pragma unroll
        for (int ks = 0; ks < 4; ks++)
            af[ks] = bnrelu8(a[ks], sc, sh, ks * 32 + ko * 8);
        int n_g = tile * 16 + nl;
#pragma unroll
        for (int jg = 0; jg < 4; jg++) {
            f32x4 acc = {0.f, 0.f, 0.f, 0.f};
#pragma unroll
            for (int ks = 0; ks < 4; ks++)
                acc = __builtin_amdgcn_mfma_f32_16x16x32_bf16(bfr[jg][ks], af[ks], acc, 0, 0, 0);
            float v0 = acc[0] + bias4[jg].x;
            float v1 = acc[1] + bias4[jg].y;
            float v2 = acc[2] + bias4[jg].z;
            float v3 = acc[3] + bias4[jg].w;
            if (jh == 0) {
                uint2 pk;
                pk.x = (unsigned)f2bf(v0) | ((unsigned)f2bf(v1) << 16);
                pk.y = (unsigned)f2bf(v2) | ((unsigned)f2bf(v3) << 16);
                *(uint2*)(pb + (size_t)n_g * 64 + jg * 16 + ko * 4) = pk;
            } else {
                float4 o = make_float4(v0, v1, v2, v3);
                *(float4*)(outf + (size_t)n_g * 64 + jg * 16 + ko * 4) = o;
            }
        }
#pragma unroll
        for (int ks = 0; ks < 4; ks++) a[ks] = an[ks];
        tile = nxt;
    }
}

// ---------------- agg2: CSR-reuse gather of p rows, FULL-bucket 512-thread blocks ----
__global__ __launch_bounds__(512) void agg2_kernel(
    const unsigned short* __restrict__ permG, const int* __restrict__ gcur,
    const unsigned short* __restrict__ degG, const unsigned short* __restrict__ startG,
    const unsigned short* __restrict__ pb, float* __restrict__ out)
{
    __shared__ __align__(4) unsigned short permL[CAP];
    __shared__ int startL[64];
    __shared__ int degL[64];
    int b = blockIdx.x, tid = threadIdx.x;
    int cnt = gcur[b];
    if (tid < 64) {
        startL[tid] = startG[b * 64 + tid];
        degL[tid] = degG[b * 64 + tid];
    }
    int cu = (cnt + 1) >> 1;
    const unsigned* pgb = (const unsigned*)(permG + (size_t)b * CAP);
    for (int i = tid; i < cu; i += 512)
        ((unsigned*)permL)[i] = pgb[i];
    __syncthreads();
    int lane = tid & 63, w = tid >> 6;
    int g = lane >> 3;
    int q = lane & 7;
    int ln = w * 8 + g;                    // 0..63
    int node = b * 64 + ln;
    const unsigned short* fbase = pb + q * 8;
    int rs = startL[ln];
    int deg = degL[ln];
    float acc[8];
#pragma unroll
    for (int t = 0; t < 8; t++) acc[t] = 0.f;
    int i = 0;
    for (; i + 3 < deg; i += 4) {
        int s0 = permL[rs + i];
        int s1 = permL[rs + i + 1];
        int s2 = permL[rs + i + 2];
        int s3 = permL[rs + i + 3];
        uint4 v0 = *(const uint4*)(fbase + (size_t)s0 * 64);
        uint4 v1 = *(const uint4*)(fbase + (size_t)s1 * 64);
        uint4 v2 = *(const uint4*)(fbase + (size_t)s2 * 64);
        uint4 v3 = *(const uint4*)(fbase + (size_t)s3 * 64);
        ACC8(v0) ACC8(v1) ACC8(v2) ACC8(v3)
    }
    for (; i < deg; i++) {
        int s0 = permL[rs + i];
        uint4 v0 = *(const uint4*)(fbase + (size_t)s0 * 64);
        ACC8(v0)
    }
    if (node < NN) {
        float inv = (deg > 0) ? (1.0f / (float)deg) : 0.f;
        float4* op = (float4*)(out + (size_t)node * 64 + q * 8);
        float4 o0 = op[0], o1 = op[1];
        o0.x += acc[0] * inv; o0.y += acc[1] * inv;
        o0.z += acc[2] * inv; o0.w += acc[3] * inv;
        o1.x += acc[4] * inv; o1.y += acc[5] * inv;
        o1.z += acc[6] * inv; o1.w += acc[7] * inv;
        op[0] = o0; op[1] = o1;
    }
}

extern "C" void kernel_launch(void* const* d_in, const int* in_sizes, int n_in,
                              void* d_out, int out_size, void* d_ws, size_t ws_size,
                              hipStream_t stream) {
    const float* x     = (const float*)d_in[0];
    const int*   ei    = (const int*)d_in[1];
    const float* W1l   = (const float*)d_in[2];
    const float* b1    = (const float*)d_in[3];
    const float* W1r   = (const float*)d_in[4];
    const float* gamma = (const float*)d_in[5];
    const float* beta  = (const float*)d_in[6];
    const float* W2l   = (const float*)d_in[7];
    const float* b2    = (const float*)d_in[8];
    const float* W2r   = (const float*)d_in[9];
    float* out = (float*)d_out;

    // workspace layout (~32.5 MB)
    char* wsb = (char*)d_ws;
    int*   gcur    = (int*)wsb;                                  // 784 ints (pad 4KB)
    float* sums_p  = (float*)(wsb + 4096);                       // 8*128 f32 (4 KB)
    float* sumsq_p = (float*)(wsb + 8192);                       // 8*128 f32 (4 KB)
    unsigned* pairs = (unsigned*)(wsb + 12288);                  // NBK*CAP u32 (4.4 MB)
    unsigned short* permG  = (unsigned short*)((char*)pairs + (size_t)NBK * CAP * 4); // u16
    unsigned short* degG   = permG + (size_t)NBK * CAP;          // NBK*64 u16
    unsigned short* startG = degG + (size_t)NBK * 64;            // NBK*64 u16
    unsigned short* xb     = startG + (size_t)NBK * 64;          // NN*64 bf16 (6.4 MB)
    unsigned short* hpreb  = xb + (size_t)NN * 64;               // NN*128 bf16 (12.8 MB)
    unsigned short* pbuf   = hpreb + (size_t)NN * 128;           // NN*64 bf16 (6.4 MB)
    unsigned short* BT1    = pbuf + (size_t)NN * 64;             // 128*128 bf16
    unsigned short* BT2    = BT1 + 128 * 128;                    // 128*128 bf16

    const int* srcp = ei;
    const int* dstp = ei + NE;

    // zero gcur + sums_p + sumsq_p
    hipMemsetAsync(d_ws, 0, 12288, stream);

    prep_bin_kernel<<<HB + XB + 64, 256, 0, stream>>>(x, xb, W1l, W1r, W2l, W2r,
                                                      BT1, BT2, srcp, dstp, gcur, pairs);
    // aggA + conv1 fused, full-bucket 512-thread blocks
    agg_conv1_kernel<<<NBK, 512, 0, stream>>>(pairs, gcur, xb, BT1, b1, hpreb,
                                              sums_p, sumsq_p, permG, degG, startG);
    // conv2 (BN fused on A-load): p bf16 -> pbuf, self+b2 -> out
    conv2_kernel<<<512, 256, 0, stream>>>(hpreb, BT2, b2, pbuf, out,
                                          sums_p, sumsq_p, gamma, beta);
    // agg2: CSR-reuse gather pbuf rows -> out += mean, full-bucket 512-thread blocks
    agg2_kernel<<<NBK, 512, 0, stream>>>(permG, gcur, degG, startG, pbuf, out);
}